// Round 4
// baseline (563.357 us; speedup 1.0000x reference)
//
#include <hip/hip_runtime.h>
#include <math.h>

#define NB 256
#define NV 32000
#define ND 1024
#define NT 64

// ---- GEMM config ----
#define GN 64
#define ASTR 56            // padded row stride (f16) for A lds tile
#define NKB 64             // 1024/16 k-blocks
#define ASLAB (256 * ASTR) // f16 per k-block slab = 14336 (28672 B)
#define NGBLK (NV / GN)    // 500
#define INV2048F 4.8828125e-4f

// ---- sampling config ----
#define NBIN 1024
#define BSH 20
#define FIX2 4294967296.0   // 2^32
#define PACK1 (1ull << 48)
#define SMASK ((1ull << 48) - 1ull)
#define MAXCAP 4096

typedef _Float16 f16x8 __attribute__((ext_vector_type(8)));
typedef _Float16 f16x4 __attribute__((ext_vector_type(4)));
typedef float f32x16 __attribute__((ext_vector_type(16)));
typedef __attribute__((address_space(3))) void lds_void;
typedef __attribute__((address_space(1))) void glb_void;

struct RowP {
  float invZ; unsigned hiKey; unsigned loKey; unsigned bs;
  unsigned ChiBin; unsigned CloBin; int ktop; unsigned pad0;
  unsigned long long ShiFix; unsigned long long toppZfix;
  unsigned long long pad1; unsigned long long pad2;
};  // 64 B

__device__ __forceinline__ unsigned mono_enc(float f) {
  unsigned u = __float_as_uint(f);
  return (u & 0x80000000u) ? ~u : (u | 0x80000000u);
}
__device__ __forceinline__ float mono_dec(unsigned u) {
  return (u & 0x80000000u) ? __uint_as_float(u & 0x7FFFFFFFu) : __uint_as_float(~u);
}

// ---------------- convert A: LDS-staged slab build, coalesced output ----------------
__global__ __launch_bounds__(256) void convert_A(const float* __restrict__ hidden,
                                                 _Float16* __restrict__ A3) {
  const int kb = blockIdx.x, t = threadIdx.x;
  __shared__ _Float16 slab[ASLAB];  // 28672 B
#pragma unroll
  for (int it = 0; it < 4; it++) {
    const int m = it * 64 + (t >> 2);
    const int k4 = (t & 3) * 4;
    float4 a4 = *(const float4*)(hidden + (size_t)m * ND + kb * 16 + k4);
    _Float16* base = slab + m * ASTR;
    float v[4] = {a4.x, a4.y, a4.z, a4.w};
#pragma unroll
    for (int q = 0; q < 4; q++) {
      const _Float16 h = (_Float16)v[q];
      const _Float16 l2 = (_Float16)((v[q] - (float)h) * 2048.0f);
      const int kk = k4 + q;
      base[kk] = h;
      base[16 + 2 * kk] = h;
      base[17 + 2 * kk] = l2;
    }
  }
  __syncthreads();
  const uint4* s = (const uint4*)slab;
  uint4* g = (uint4*)(A3 + (size_t)kb * ASLAB);
#pragma unroll
  for (int i = 0; i < 7; i++) g[i * 256 + t] = s[i * 256 + t];
}

// ---------------- MFMA f16-split GEMM (unchanged from round 3) ----------------
__global__ __launch_bounds__(256, 2) void gemm_f16s(
    const float* __restrict__ Bm, const _Float16* __restrict__ A3,
    const float* __restrict__ temp, unsigned* __restrict__ pmax,
    float* __restrict__ C) {
  __shared__ _Float16 Als[ASLAB];
  __shared__ _Float16 Bls[GN * ASTR];
  __shared__ float s_invT[256];
  __shared__ unsigned s_pm[256];

  const int t = threadIdx.x;
  const int l = t & 63, w = t >> 6;
  const int n0 = blockIdx.x * GN;
  s_invT[t] = 1.0f / temp[t];
  s_pm[t] = 0u;

  f32x16 accA[2][2] = {};
  f32x16 accB[2][2] = {};

  const int bn = t >> 2, bk4 = (t & 3) * 4;
  const int l31 = l & 31, lh = l >> 5;
  const int ka = lh * 8;
  const int mb = w * 64;

  for (int kb = 0; kb < NKB; kb++) {
    {
      const char* ga = (const char*)A3 + (size_t)kb * (ASLAB * 2) + (w * 7) * 1024 + l * 16;
      char* la = (char*)Als + (w * 7) * 1024;
#pragma unroll
      for (int i = 0; i < 7; i++)
        __builtin_amdgcn_global_load_lds((const glb_void*)(ga + i * 1024),
                                         (lds_void*)(la + i * 1024), 16, 0, 0);
    }
    {
      const float4 bv = *(const float4*)(Bm + (size_t)(n0 + bn) * ND + kb * 16 + bk4);
      const _Float16 h0 = (_Float16)bv.x, h1 = (_Float16)bv.y,
                     h2 = (_Float16)bv.z, h3 = (_Float16)bv.w;
      const _Float16 l0 = (_Float16)((bv.x - (float)h0) * 2048.0f);
      const _Float16 l1 = (_Float16)((bv.y - (float)h1) * 2048.0f);
      const _Float16 l2 = (_Float16)((bv.z - (float)h2) * 2048.0f);
      const _Float16 l3 = (_Float16)((bv.w - (float)h3) * 2048.0f);
      _Float16* prow = Bls + bn * ASTR;
      *(f16x4*)(prow + bk4) = (f16x4){h0, h1, h2, h3};
      *(f16x8*)(prow + 16 + 2 * bk4) = (f16x8){l0, h0, l1, h1, l2, h2, l3, h3};
    }
    __syncthreads();
    {
      const _Float16* Ap = Als + (size_t)(mb + l31) * ASTR + ka;
      const _Float16* Bp = Bls + (size_t)l31 * ASTR + ka;
      f16x8 a0 = *(const f16x8*)(Ap);
      f16x8 a1 = *(const f16x8*)(Ap + 32 * ASTR);
      f16x8 b0 = *(const f16x8*)(Bp);
      f16x8 b1 = *(const f16x8*)(Bp + 32 * ASTR);
      accA[0][0] = __builtin_amdgcn_mfma_f32_32x32x16_f16(a0, b0, accA[0][0], 0, 0, 0);
      accA[0][1] = __builtin_amdgcn_mfma_f32_32x32x16_f16(a0, b1, accA[0][1], 0, 0, 0);
      accA[1][0] = __builtin_amdgcn_mfma_f32_32x32x16_f16(a1, b0, accA[1][0], 0, 0, 0);
      accA[1][1] = __builtin_amdgcn_mfma_f32_32x32x16_f16(a1, b1, accA[1][1], 0, 0, 0);
#pragma unroll
      for (int s = 0; s < 2; s++) {
        const int off = 16 + s * 16;
        f16x8 c0 = *(const f16x8*)(Ap + off);
        f16x8 c1 = *(const f16x8*)(Ap + 32 * ASTR + off);
        f16x8 d0 = *(const f16x8*)(Bp + off);
        f16x8 d1 = *(const f16x8*)(Bp + 32 * ASTR + off);
        accB[0][0] = __builtin_amdgcn_mfma_f32_32x32x16_f16(c0, d0, accB[0][0], 0, 0, 0);
        accB[0][1] = __builtin_amdgcn_mfma_f32_32x32x16_f16(c0, d1, accB[0][1], 0, 0, 0);
        accB[1][0] = __builtin_amdgcn_mfma_f32_32x32x16_f16(c1, d0, accB[1][0], 0, 0, 0);
        accB[1][1] = __builtin_amdgcn_mfma_f32_32x32x16_f16(c1, d1, accB[1][1], 0, 0, 0);
      }
    }
    __syncthreads();
  }

#pragma unroll
  for (int mi = 0; mi < 2; mi++) {
#pragma unroll
    for (int r = 0; r < 16; r++) {
      const int row = mb + mi * 32 + (r & 3) + 8 * (r >> 2) + 4 * lh;
      const float it = s_invT[row];
      float v0 = (accA[mi][0][r] + accB[mi][0][r] * INV2048F) * it;
      float v1 = (accA[mi][1][r] + accB[mi][1][r] * INV2048F) * it;
      C[(size_t)row * NV + n0 + l31] = v0;
      C[(size_t)row * NV + n0 + 32 + l31] = v1;
      float mx = fmaxf(v0, v1);
#pragma unroll
      for (int o = 1; o < 32; o <<= 1) mx = fmaxf(mx, __shfl_xor(mx, o));
      if (l31 == 0) atomicMax(&s_pm[row], mono_enc(mx));
    }
  }
  __syncthreads();
  pmax[(size_t)blockIdx.x * 256 + t] = s_pm[t];
}

// ---------------- S0: row max reduce + apply penalties in-place to x ----------------
__global__ __launch_bounds__(512) void s0_prep(
    const unsigned* __restrict__ pmax, const int* __restrict__ toks,
    const float* __restrict__ pres, const float* __restrict__ freq,
    const float* __restrict__ temp, float* __restrict__ Mrow,
    float* __restrict__ buf) {
  const int b = blockIdx.x, t = threadIdx.x;
  __shared__ unsigned su[8];
  __shared__ int s_tok[NT];
  unsigned um = 0u;
  for (int i = t; i < NGBLK; i += 512) um = max(um, pmax[(size_t)i * 256 + b]);
#pragma unroll
  for (int o = 32; o; o >>= 1) um = max(um, (unsigned)__shfl_down(um, o));
  if ((t & 63) == 0) su[t >> 6] = um;
  if (t < NT) s_tok[t] = toks[b * NT + t];
  __syncthreads();
  if (t == 0) {
    unsigned m = su[0];
#pragma unroll
    for (int w = 1; w < 8; w++) m = max(m, su[w]);
    Mrow[b] = mono_dec(m);
  }
  if (t < NT) {
    const int tk = s_tok[t];
    bool first = true; int cnt = 0;
    for (int j = 0; j < NT; j++)
      if (s_tok[j] == tk) { if (j < t) first = false; cnt++; }
    if (first) {
      const float invT = 1.0f / temp[b];
      buf[(size_t)b * NV + tk] -= (freq[b] * (float)cnt + pres[b]) * invT;
    }
  }
}

// ---------------- S1: exp + packed (count|sum) histogram, merge nonzero bins ----------
__global__ __launch_bounds__(256) void s1_hist(
    const float* __restrict__ buf, const float* __restrict__ Mrow,
    unsigned long long* __restrict__ histP) {
  const int b = blockIdx.x >> 3, sl = blockIdx.x & 7, t = threadIdx.x;
  __shared__ unsigned long long h[NBIN];
  for (int i = t; i < NBIN; i += 256) h[i] = 0ull;
  __syncthreads();
  const float M = Mrow[b];
  const float* row = buf + (size_t)b * NV;
  const int base = sl * 4096;
#pragma unroll
  for (int it = 0; it < 4; it++) {
    const int idx = base + (it * 256 + t) * 4;
    if (idx < NV) {
      float4 x4 = *(const float4*)(row + idx);
      float e0 = expf(x4.x - M), e1 = expf(x4.y - M);
      float e2 = expf(x4.z - M), e3 = expf(x4.w - M);
      unsigned k;
      k = __float_as_uint(e0); if (k) atomicAdd(&h[k >> BSH], PACK1 | (unsigned long long)(e0 * FIX2));
      k = __float_as_uint(e1); if (k) atomicAdd(&h[k >> BSH], PACK1 | (unsigned long long)(e1 * FIX2));
      k = __float_as_uint(e2); if (k) atomicAdd(&h[k >> BSH], PACK1 | (unsigned long long)(e2 * FIX2));
      k = __float_as_uint(e3); if (k) atomicAdd(&h[k >> BSH], PACK1 | (unsigned long long)(e3 * FIX2));
    }
  }
  __syncthreads();
  unsigned long long* gh = histP + (size_t)b * NBIN;
  for (int i = t; i < NBIN; i += 256)
    if (h[i]) atomicAdd(&gh[i], h[i]);
}

// ---------------- S2: suffix-scan bins, locate cutoff bin, emit row params ----------
__global__ __launch_bounds__(256) void s2_cut(
    const unsigned long long* __restrict__ histP,
    const float* __restrict__ topp_a, const int* __restrict__ topk_a,
    RowP* __restrict__ params) {
  const int b = blockIdx.x, t = threadIdx.x;
  __shared__ unsigned long long suf[NBIN];
  __shared__ unsigned long long sc[256];
  __shared__ int s_bs;
  const unsigned long long* hp = histP + (size_t)b * NBIN;
  unsigned long long v[4];
#pragma unroll
  for (int i = 0; i < 4; i++) v[i] = hp[t * 4 + i];
  sc[t] = v[0] + v[1] + v[2] + v[3];
  __syncthreads();
  for (int off = 1; off < 256; off <<= 1) {
    unsigned long long add = (t + off < 256) ? sc[t + off] : 0ull;
    __syncthreads();
    sc[t] += add;
    __syncthreads();
  }
  const unsigned long long totalP = sc[0];
  unsigned long long run = (t < 255) ? sc[t + 1] : 0ull;
  suf[t * 4 + 3] = run; run += v[3];
  suf[t * 4 + 2] = run; run += v[2];
  suf[t * 4 + 1] = run; run += v[1];
  suf[t * 4 + 0] = run;
  __syncthreads();

  const int ktop = topk_a[b];
  const double toppd = (double)topp_a[b];
  unsigned long long Zfix = totalP & SMASK;
  if (!Zfix) Zfix = 1ull;
  const unsigned totalC = (unsigned)(totalP >> 48);
  const unsigned long long toppZfix = (unsigned long long)(toppd * (double)Zfix);

#pragma unroll
  for (int i = 0; i < 4; i++) {
    const int bin = t * 4 + i;
    const unsigned long long s1 = suf[bin];
    const bool A = ((int)(s1 >> 48) < ktop) && ((s1 & SMASK) <= toppZfix);
    bool Ap = false;
    if (bin > 0) {
      const unsigned long long s0 = suf[bin - 1];
      Ap = ((int)(s0 >> 48) < ktop) && ((s0 & SMASK) <= toppZfix);
    }
    if (A && !Ap) s_bs = bin;
  }
  __syncthreads();
  if (t == 0) {
    const int bs = s_bs;
    RowP p;
    p.bs = bs;
    p.hiKey = (((unsigned)(bs + 1)) << BSH) - 1u;
    p.loKey = bs ? ((((unsigned)bs) << BSH) - 1u) : 0u;
    const unsigned long long shp = suf[bs];
    p.ChiBin = (unsigned)(shp >> 48);
    p.ShiFix = shp & SMASK;
    p.CloBin = bs ? (unsigned)(suf[bs - 1] >> 48) : totalC;
    p.ktop = ktop;
    p.toppZfix = toppZfix;
    p.invZ = (float)(FIX2 / (double)Zfix);
    p.pad0 = 0; p.pad1 = 0; p.pad2 = 0;
    params[b] = p;
  }
}

// ---------------- S3: filter pass — definite keep/zero, sentinel + collect in-bin ----
__global__ __launch_bounds__(256) void s3_filter(
    float* __restrict__ buf, const float* __restrict__ Mrow,
    const RowP* __restrict__ params, unsigned long long* __restrict__ cand,
    int* __restrict__ ncand, int CAP) {
  const int b = blockIdx.x >> 3, sl = blockIdx.x & 7, t = threadIdx.x;
  const RowP p = params[b];
  const float M = Mrow[b], invZ = p.invZ;
  const unsigned hiKey = p.hiKey, loKey = p.loKey;
  float* row = buf + (size_t)b * NV;
  unsigned long long* cb = cand + (size_t)b * CAP;
  const int base = sl * 4096;
#pragma unroll
  for (int it = 0; it < 4; it++) {
    const int idx = base + (it * 256 + t) * 4;
    if (idx < NV) {
      float4 x4 = *(const float4*)(row + idx);
      float4 o4;
      {
        const float e = expf(x4.x - M); const unsigned k = __float_as_uint(e);
        float o = (k > hiKey) ? e * invZ : 0.f;
        if (k > loKey && k <= hiKey) {
          const int j = atomicAdd(&ncand[b], 1);
          if (j < CAP) cb[j] = ((unsigned long long)k << 32) | (unsigned)idx;
          o = -e;
        }
        o4.x = o;
      }
      {
        const float e = expf(x4.y - M); const unsigned k = __float_as_uint(e);
        float o = (k > hiKey) ? e * invZ : 0.f;
        if (k > loKey && k <= hiKey) {
          const int j = atomicAdd(&ncand[b], 1);
          if (j < CAP) cb[j] = ((unsigned long long)k << 32) | (unsigned)(idx + 1);
          o = -e;
        }
        o4.y = o;
      }
      {
        const float e = expf(x4.z - M); const unsigned k = __float_as_uint(e);
        float o = (k > hiKey) ? e * invZ : 0.f;
        if (k > loKey && k <= hiKey) {
          const int j = atomicAdd(&ncand[b], 1);
          if (j < CAP) cb[j] = ((unsigned long long)k << 32) | (unsigned)(idx + 2);
          o = -e;
        }
        o4.z = o;
      }
      {
        const float e = expf(x4.w - M); const unsigned k = __float_as_uint(e);
        float o = (k > hiKey) ? e * invZ : 0.f;
        if (k > loKey && k <= hiKey) {
          const int j = atomicAdd(&ncand[b], 1);
          if (j < CAP) cb[j] = ((unsigned long long)k << 32) | (unsigned)(idx + 3);
          o = -e;
        }
        o4.w = o;
      }
      *(float4*)(row + idx) = o4;
    }
  }
}

// ---------------- S4: exact cutoff via candidate bisection + tie-rank scatter ----------
__global__ __launch_bounds__(256) void s4_resolve(
    float* __restrict__ buf, const RowP* __restrict__ params,
    const unsigned long long* __restrict__ cand, const int* __restrict__ ncand_g,
    int CAP) {
  const int b = blockIdx.x, t = threadIdx.x;
  const int lane = t & 63, wv = t >> 6;
  const RowP p = params[b];
  float* row = buf + (size_t)b * NV;
  const int nc = ncand_g[b];
  __shared__ unsigned ck[MAXCAP];
  __shared__ unsigned ci[MAXCAP];
  __shared__ unsigned long long sP[4][16];
  __shared__ unsigned long long sT[16];
  __shared__ int s_rank[256];

  unsigned lo = p.loKey, hi = p.hiKey;
  long long Chi = (long long)p.ChiBin, Clo = (long long)p.CloBin;
  unsigned long long Shi = p.ShiFix;
  const unsigned long long toppZ = p.toppZfix;
  const int ktop = p.ktop;
  const float invZ = p.invZ;
  const long long ChiB = (long long)p.ChiBin;
  const unsigned long long ShiB = p.ShiFix;

  if (nc <= CAP) {
    for (int j = t; j < nc; j += 256) {
      const unsigned long long cd = cand[(size_t)b * CAP + j];
      ck[j] = (unsigned)(cd >> 32);
      ci[j] = (unsigned)cd;
    }
    __syncthreads();
    while (hi - lo > 1u) {
      const unsigned step = ((hi - lo) + 15u) >> 4;
      unsigned u[15];
#pragma unroll
      for (int i = 0; i < 15; i++) {
        unsigned ui = lo + (unsigned)(i + 1) * step;
        u[i] = (ui > hi) ? hi : ui;
      }
      unsigned long long acc[15];
#pragma unroll
      for (int i = 0; i < 15; i++) acc[i] = 0ull;
      for (int j = t; j < nc; j += 256) {
        const unsigned k = ck[j];
        const unsigned long long pv = PACK1 | (unsigned long long)(__uint_as_float(k) * FIX2);
#pragma unroll
        for (int i = 0; i < 15; i++)
          if (k > u[i]) acc[i] += pv;
      }
#pragma unroll
      for (int i = 0; i < 15; i++) {
        unsigned long long a = acc[i];
#pragma unroll
        for (int o = 32; o; o >>= 1) a += __shfl_down(a, o);
        if (lane == 0) sP[wv][i] = a;
      }
      __syncthreads();
      if (t < 15) {
        unsigned long long a = 0ull;
#pragma unroll
        for (int w = 0; w < 4; w++) a += sP[w][t];
        sT[t] = a;
      }
      __syncthreads();
      for (int i = 0; i < 15; i++) {
        const unsigned long long a = sT[i];
        const long long c = ChiB + (long long)(a >> 48);
        const unsigned long long s = ShiB + (a & SMASK);
        const bool At = (c < ktop) && (s <= toppZ);
        if (At) { Chi = c; Shi = s; hi = u[i]; break; }
        if (u[i] < hi) { lo = u[i]; Clo = c; }
      }
      __syncthreads();
    }
    const unsigned ustar = hi;
    long long m = Clo - Chi;
    {
      const long long lim = (long long)ktop - Chi;
      if (lim < m) m = lim;
      const double tcut = (double)__uint_as_float(ustar) * FIX2;
      const double rem = (double)(toppZ - Shi);
      const double Rd = floor(rem / tcut) + 1.0;
      if (Rd < (double)m) m = (long long)Rd;
    }
    if (m < 1) m = 1;
    for (int j = t; j < nc; j += 256) {
      const unsigned k = ck[j];
      const unsigned idx = ci[j];
      float val = 0.f;
      if (k > ustar) val = __uint_as_float(k) * invZ;
      else if (k == ustar) {
        int r = 0;
        for (int q = 0; q < nc; q++) r += (ck[q] == ustar && ci[q] < idx);
        if (r < m) val = __uint_as_float(k) * invZ;
      }
      row[idx] = val;
    }
  } else {
    // fallback: resolve over sentinel negatives with full-row scans (rare)
    while (hi - lo > 1u) {
      const unsigned step = ((hi - lo) + 15u) >> 4;
      unsigned u[15];
#pragma unroll
      for (int i = 0; i < 15; i++) {
        unsigned ui = lo + (unsigned)(i + 1) * step;
        u[i] = (ui > hi) ? hi : ui;
      }
      unsigned long long acc[15];
#pragma unroll
      for (int i = 0; i < 15; i++) acc[i] = 0ull;
      for (int v = t; v < NV; v += 256) {
        const float f = row[v];
        if (f < 0.f) {
          const float e = -f;
          const unsigned k = __float_as_uint(e);
          const unsigned long long pv = PACK1 | (unsigned long long)(e * FIX2);
#pragma unroll
          for (int i = 0; i < 15; i++)
            if (k > u[i]) acc[i] += pv;
        }
      }
#pragma unroll
      for (int i = 0; i < 15; i++) {
        unsigned long long a = acc[i];
#pragma unroll
        for (int o = 32; o; o >>= 1) a += __shfl_down(a, o);
        if (lane == 0) sP[wv][i] = a;
      }
      __syncthreads();
      if (t < 15) {
        unsigned long long a = 0ull;
#pragma unroll
        for (int w = 0; w < 4; w++) a += sP[w][t];
        sT[t] = a;
      }
      __syncthreads();
      for (int i = 0; i < 15; i++) {
        const unsigned long long a = sT[i];
        const long long c = ChiB + (long long)(a >> 48);
        const unsigned long long s = ShiB + (a & SMASK);
        const bool At = (c < ktop) && (s <= toppZ);
        if (At) { Chi = c; Shi = s; hi = u[i]; break; }
        if (u[i] < hi) { lo = u[i]; Clo = c; }
      }
      __syncthreads();
    }
    const unsigned ustar = hi;
    long long m = Clo - Chi;
    {
      const long long lim = (long long)ktop - Chi;
      if (lim < m) m = lim;
      const double tcut = (double)__uint_as_float(ustar) * FIX2;
      const double rem = (double)(toppZ - Shi);
      const double Rd = floor(rem / tcut) + 1.0;
      if (Rd < (double)m) m = (long long)Rd;
    }
    if (m < 1) m = 1;

    const int CH = (NV + 255) / 256;
    const int base = t * CH;
    const int end = (base + CH < NV) ? base + CH : NV;
    int myc = 0;
    for (int v = base; v < end; v++) {
      const float f = row[v];
      if (f < 0.f && __float_as_uint(-f) == ustar) myc++;
    }
    s_rank[t] = myc;
    __syncthreads();
    for (int off = 1; off < 256; off <<= 1) {
      const int v0 = s_rank[t];
      const int vn = (t >= off) ? s_rank[t - off] : 0;
      __syncthreads();
      s_rank[t] = v0 + vn;
      __syncthreads();
    }
    int r = (t > 0) ? s_rank[t - 1] : 0;
    for (int v = base; v < end; v++) {
      const float f = row[v];
      if (f < 0.f) {
        const float e = -f;
        const unsigned k = __float_as_uint(e);
        float val = 0.f;
        if (k > ustar) val = e * invZ;
        else if (k == ustar) { if (r < m) val = e * invZ; r++; }
        row[v] = val;
      }
    }
  }
}

extern "C" void kernel_launch(void* const* d_in, const int* in_sizes, int n_in,
                              void* d_out, int out_size, void* d_ws, size_t ws_size,
                              hipStream_t stream) {
  (void)in_sizes; (void)n_in; (void)out_size;
  const float* hidden = (const float*)d_in[0];
  const float* emb    = (const float*)d_in[1];
  const int*   toks   = (const int*)d_in[2];
  const float* pres   = (const float*)d_in[3];
  const float* freq   = (const float*)d_in[4];
  const float* temp   = (const float*)d_in[5];
  const float* topp   = (const float*)d_in[6];
  const int*   topk   = (const int*)d_in[7];
  float* out = (float*)d_out;

  // ws layout
  const size_t offA3   = 0;                         // 1,835,008 B
  const size_t offPmax = 1835008;                   // 512,000 B
  const size_t offM    = offPmax + 512000;          // 1,024 B
  const size_t offHist = offM + 1024;               // 2,097,152 B
  const size_t offPar  = offHist + 2097152;         // 16,384 B
  const size_t offNc   = offPar + 16384;            // 1,024 B
  const size_t offCand = offNc + 1024;

  _Float16* A3 = (_Float16*)((char*)d_ws + offA3);
  unsigned* pmax = (unsigned*)((char*)d_ws + offPmax);
  float* Mrow = (float*)((char*)d_ws + offM);
  unsigned long long* histP = (unsigned long long*)((char*)d_ws + offHist);
  RowP* params = (RowP*)((char*)d_ws + offPar);
  int* ncand = (int*)((char*)d_ws + offNc);
  unsigned long long* cand = (unsigned long long*)((char*)d_ws + offCand);

  int CAP = MAXCAP;
  if (ws_size > offCand) {
    const size_t avail = (ws_size - offCand) / (256ull * 8ull);
    if ((size_t)CAP > avail) CAP = (int)avail;
  } else CAP = 0;
  if (CAP < 1) CAP = 1;

  hipMemsetAsync((char*)d_ws + offHist, 0, 2097152 + 16384 + 1024, stream);
  convert_A<<<NKB, 256, 0, stream>>>(hidden, A3);
  gemm_f16s<<<NGBLK, 256, 0, stream>>>(emb, A3, temp, pmax, out);
  s0_prep<<<NB, 512, 0, stream>>>(pmax, toks, pres, freq, temp, Mrow, out);
  s1_hist<<<NB * 8, 256, 0, stream>>>(out, Mrow, histP);
  s2_cut<<<NB, 256, 0, stream>>>(histP, topp, topk, params);
  s3_filter<<<NB * 8, 256, 0, stream>>>(out, Mrow, params, cand, ncand, CAP);
  s4_resolve<<<NB, 256, 0, stream>>>(out, params, cand, ncand, CAP);
}

// Round 5
// 334.622 us; speedup vs baseline: 1.6836x; 1.6836x over previous
//
#include <hip/hip_runtime.h>
#include <math.h>

#define NB 256
#define NV 32000
#define ND 1024
#define NT 64

// ---- GEMM config ----
#define GN 64
#define ASTR 56            // padded row stride (f16) for A lds tile
#define NKB 64             // 1024/16 k-blocks
#define ASLAB (256 * ASTR) // f16 per k-block slab = 14336 (28672 B)
#define NGBLK (NV / GN)    // 500
#define INV2048F 4.8828125e-4f

// ---- sampling config ----
#define NBIN 1024
#define FIX2 4294967296.0   // 2^32
#define PACK1 (1ull << 48)
#define SMASK ((1ull << 48) - 1ull)

typedef _Float16 f16x8 __attribute__((ext_vector_type(8)));
typedef _Float16 f16x4 __attribute__((ext_vector_type(4)));
typedef float f32x16 __attribute__((ext_vector_type(16)));
typedef __attribute__((address_space(3))) void lds_void;
typedef __attribute__((address_space(1))) void glb_void;

struct RowP2 {
  unsigned long long basePack;  // (count<<48 | sumfix) of elements strictly above range
  unsigned long long toppZfix;
  unsigned pfx;                 // accumulated bin path (10 bits per resolved level)
  int ktop;
  float invZ;
  unsigned ustar;
  int m;
  int cEq;
};  // 40 B

__device__ __forceinline__ unsigned mono_enc(float f) {
  unsigned u = __float_as_uint(f);
  return (u & 0x80000000u) ? ~u : (u | 0x80000000u);
}
__device__ __forceinline__ float mono_dec(unsigned u) {
  return (u & 0x80000000u) ? __uint_as_float(u & 0x7FFFFFFFu) : __uint_as_float(~u);
}

// ---------------- convert A: LDS-staged slab build, coalesced output ----------------
__global__ __launch_bounds__(256) void convert_A(const float* __restrict__ hidden,
                                                 _Float16* __restrict__ A3) {
  const int kb = blockIdx.x, t = threadIdx.x;
  __shared__ _Float16 slab[ASLAB];  // 28672 B
#pragma unroll
  for (int it = 0; it < 4; it++) {
    const int m = it * 64 + (t >> 2);
    const int k4 = (t & 3) * 4;
    float4 a4 = *(const float4*)(hidden + (size_t)m * ND + kb * 16 + k4);
    _Float16* base = slab + m * ASTR;
    float v[4] = {a4.x, a4.y, a4.z, a4.w};
#pragma unroll
    for (int q = 0; q < 4; q++) {
      const _Float16 h = (_Float16)v[q];
      const _Float16 l2 = (_Float16)((v[q] - (float)h) * 2048.0f);
      const int kk = k4 + q;
      base[kk] = h;
      base[16 + 2 * kk] = h;
      base[17 + 2 * kk] = l2;
    }
  }
  __syncthreads();
  const uint4* s = (const uint4*)slab;
  uint4* g = (uint4*)(A3 + (size_t)kb * ASLAB);
#pragma unroll
  for (int i = 0; i < 7; i++) g[i * 256 + t] = s[i * 256 + t];
}

// ---------------- MFMA f16-split GEMM: x = (hidden·emb^T)*invT, rowmax via atomics ----
__global__ __launch_bounds__(256, 2) void gemm_f16s(
    const float* __restrict__ Bm, const _Float16* __restrict__ A3,
    const float* __restrict__ temp, unsigned* __restrict__ rowmax,
    float* __restrict__ C) {
  __shared__ _Float16 Als[ASLAB];
  __shared__ _Float16 Bls[GN * ASTR];
  __shared__ float s_invT[256];
  __shared__ unsigned s_pm[256];

  const int t = threadIdx.x;
  const int l = t & 63, w = t >> 6;
  const int n0 = blockIdx.x * GN;
  s_invT[t] = 1.0f / temp[t];
  s_pm[t] = 0u;

  f32x16 accA[2][2] = {};
  f32x16 accB[2][2] = {};

  const int bn = t >> 2, bk4 = (t & 3) * 4;
  const int l31 = l & 31, lh = l >> 5;
  const int ka = lh * 8;
  const int mb = w * 64;

  for (int kb = 0; kb < NKB; kb++) {
    {
      const char* ga = (const char*)A3 + (size_t)kb * (ASLAB * 2) + (w * 7) * 1024 + l * 16;
      char* la = (char*)Als + (w * 7) * 1024;
#pragma unroll
      for (int i = 0; i < 7; i++)
        __builtin_amdgcn_global_load_lds((const glb_void*)(ga + i * 1024),
                                         (lds_void*)(la + i * 1024), 16, 0, 0);
    }
    {
      const float4 bv = *(const float4*)(Bm + (size_t)(n0 + bn) * ND + kb * 16 + bk4);
      const _Float16 h0 = (_Float16)bv.x, h1 = (_Float16)bv.y,
                     h2 = (_Float16)bv.z, h3 = (_Float16)bv.w;
      const _Float16 l0 = (_Float16)((bv.x - (float)h0) * 2048.0f);
      const _Float16 l1 = (_Float16)((bv.y - (float)h1) * 2048.0f);
      const _Float16 l2 = (_Float16)((bv.z - (float)h2) * 2048.0f);
      const _Float16 l3 = (_Float16)((bv.w - (float)h3) * 2048.0f);
      _Float16* prow = Bls + bn * ASTR;
      *(f16x4*)(prow + bk4) = (f16x4){h0, h1, h2, h3};
      *(f16x8*)(prow + 16 + 2 * bk4) = (f16x8){l0, h0, l1, h1, l2, h2, l3, h3};
    }
    __syncthreads();
    {
      const _Float16* Ap = Als + (size_t)(mb + l31) * ASTR + ka;
      const _Float16* Bp = Bls + (size_t)l31 * ASTR + ka;
      f16x8 a0 = *(const f16x8*)(Ap);
      f16x8 a1 = *(const f16x8*)(Ap + 32 * ASTR);
      f16x8 b0 = *(const f16x8*)(Bp);
      f16x8 b1 = *(const f16x8*)(Bp + 32 * ASTR);
      accA[0][0] = __builtin_amdgcn_mfma_f32_32x32x16_f16(a0, b0, accA[0][0], 0, 0, 0);
      accA[0][1] = __builtin_amdgcn_mfma_f32_32x32x16_f16(a0, b1, accA[0][1], 0, 0, 0);
      accA[1][0] = __builtin_amdgcn_mfma_f32_32x32x16_f16(a1, b0, accA[1][0], 0, 0, 0);
      accA[1][1] = __builtin_amdgcn_mfma_f32_32x32x16_f16(a1, b1, accA[1][1], 0, 0, 0);
#pragma unroll
      for (int s = 0; s < 2; s++) {
        const int off = 16 + s * 16;
        f16x8 c0 = *(const f16x8*)(Ap + off);
        f16x8 c1 = *(const f16x8*)(Ap + 32 * ASTR + off);
        f16x8 d0 = *(const f16x8*)(Bp + off);
        f16x8 d1 = *(const f16x8*)(Bp + 32 * ASTR + off);
        accB[0][0] = __builtin_amdgcn_mfma_f32_32x32x16_f16(c0, d0, accB[0][0], 0, 0, 0);
        accB[0][1] = __builtin_amdgcn_mfma_f32_32x32x16_f16(c0, d1, accB[0][1], 0, 0, 0);
        accB[1][0] = __builtin_amdgcn_mfma_f32_32x32x16_f16(c1, d0, accB[1][0], 0, 0, 0);
        accB[1][1] = __builtin_amdgcn_mfma_f32_32x32x16_f16(c1, d1, accB[1][1], 0, 0, 0);
      }
    }
    __syncthreads();
  }

#pragma unroll
  for (int mi = 0; mi < 2; mi++) {
#pragma unroll
    for (int r = 0; r < 16; r++) {
      const int row = mb + mi * 32 + (r & 3) + 8 * (r >> 2) + 4 * lh;
      const float it = s_invT[row];
      float v0 = (accA[mi][0][r] + accB[mi][0][r] * INV2048F) * it;
      float v1 = (accA[mi][1][r] + accB[mi][1][r] * INV2048F) * it;
      C[(size_t)row * NV + n0 + l31] = v0;
      C[(size_t)row * NV + n0 + 32 + l31] = v1;
      float mx = fmaxf(v0, v1);
#pragma unroll
      for (int o = 1; o < 32; o <<= 1) mx = fmaxf(mx, __shfl_xor(mx, o));
      if (l31 == 0) atomicMax(&s_pm[row], mono_enc(mx));
    }
  }
  __syncthreads();
  atomicMax(&rowmax[t], s_pm[t]);
}

// ---------------- S0: Mrow decode + apply penalties in-place to x ----------------
__global__ __launch_bounds__(64) void s0_prep(
    const unsigned* __restrict__ rowmax, const int* __restrict__ toks,
    const float* __restrict__ pres, const float* __restrict__ freq,
    const float* __restrict__ temp, float* __restrict__ Mrow,
    float* __restrict__ buf) {
  const int b = blockIdx.x, t = threadIdx.x;
  __shared__ int s_tok[NT];
  s_tok[t] = toks[b * NT + t];
  __syncthreads();
  const int tk = s_tok[t];
  bool first = true; int cnt = 0;
  for (int j = 0; j < NT; j++)
    if (s_tok[j] == tk) { if (j < t) first = false; cnt++; }
  if (first)
    buf[(size_t)b * NV + tk] -= (freq[b] * (float)cnt + pres[b]) / temp[b];
  if (t == 0) Mrow[b] = mono_dec(rowmax[b]);
}

// ---------------- H0: e = exp(x-M) written in place + level-0 histogram (k>>20) ------
__global__ __launch_bounds__(256) void h_l0(
    float* __restrict__ buf, const float* __restrict__ Mrow,
    unsigned long long* __restrict__ histP) {
  const int b = blockIdx.x >> 3, sl = blockIdx.x & 7, t = threadIdx.x;
  __shared__ unsigned long long h[NBIN];
  for (int i = t; i < NBIN; i += 256) h[i] = 0ull;
  __syncthreads();
  const float M = Mrow[b];
  float* row = buf + (size_t)b * NV;
  const int base = sl * 4096;
#pragma unroll
  for (int it = 0; it < 4; it++) {
    const int idx = base + (it * 256 + t) * 4;
    if (idx < NV) {
      float4 x4 = *(const float4*)(row + idx);
      float4 e4;
      e4.x = expf(x4.x - M); e4.y = expf(x4.y - M);
      e4.z = expf(x4.z - M); e4.w = expf(x4.w - M);
      *(float4*)(row + idx) = e4;
      unsigned k;
      k = __float_as_uint(e4.x); if (k) atomicAdd(&h[k >> 20], PACK1 | (unsigned long long)(e4.x * FIX2));
      k = __float_as_uint(e4.y); if (k) atomicAdd(&h[k >> 20], PACK1 | (unsigned long long)(e4.y * FIX2));
      k = __float_as_uint(e4.z); if (k) atomicAdd(&h[k >> 20], PACK1 | (unsigned long long)(e4.z * FIX2));
      k = __float_as_uint(e4.w); if (k) atomicAdd(&h[k >> 20], PACK1 | (unsigned long long)(e4.w * FIX2));
    }
  }
  __syncthreads();
  unsigned long long* gh = histP + (size_t)b * NBIN;
  for (int i = t; i < NBIN; i += 256)
    if (h[i]) atomicAdd(&gh[i], h[i]);
}

// ---------------- H-refine: histogram restricted to current prefix range ------------
__global__ __launch_bounds__(256) void h_ref(
    const float* __restrict__ buf, const RowP2* __restrict__ params,
    unsigned long long* __restrict__ histP, int matchShift, int binShift) {
  const int b = blockIdx.x >> 3, sl = blockIdx.x & 7, t = threadIdx.x;
  __shared__ unsigned long long h[NBIN];
  for (int i = t; i < NBIN; i += 256) h[i] = 0ull;
  __syncthreads();
  const unsigned pfx = params[b].pfx;
  const float* row = buf + (size_t)b * NV;
  const int base = sl * 4096;
#pragma unroll
  for (int it = 0; it < 4; it++) {
    const int idx = base + (it * 256 + t) * 4;
    if (idx < NV) {
      float4 e4 = *(const float4*)(row + idx);
      unsigned k;
      k = __float_as_uint(e4.x); if (k && (k >> matchShift) == pfx) atomicAdd(&h[(k >> binShift) & 1023u], PACK1 | (unsigned long long)(e4.x * FIX2));
      k = __float_as_uint(e4.y); if (k && (k >> matchShift) == pfx) atomicAdd(&h[(k >> binShift) & 1023u], PACK1 | (unsigned long long)(e4.y * FIX2));
      k = __float_as_uint(e4.z); if (k && (k >> matchShift) == pfx) atomicAdd(&h[(k >> binShift) & 1023u], PACK1 | (unsigned long long)(e4.z * FIX2));
      k = __float_as_uint(e4.w); if (k && (k >> matchShift) == pfx) atomicAdd(&h[(k >> binShift) & 1023u], PACK1 | (unsigned long long)(e4.w * FIX2));
    }
  }
  __syncthreads();
  unsigned long long* gh = histP + (size_t)b * NBIN;
  for (int i = t; i < NBIN; i += 256)
    if (h[i]) atomicAdd(&gh[i], h[i]);
}

// ---------------- S2: suffix-scan bins, descend one level (also zeroes hist) --------
__global__ __launch_bounds__(256) void s2_level(
    unsigned long long* __restrict__ histP, const float* __restrict__ topp_a,
    const int* __restrict__ topk_a, RowP2* __restrict__ params, int level) {
  const int b = blockIdx.x, t = threadIdx.x;
  __shared__ unsigned long long suf[NBIN];
  __shared__ unsigned long long sc[256];
  __shared__ int s_bs;
  unsigned long long* hp = histP + (size_t)b * NBIN;
  unsigned long long v[4];
#pragma unroll
  for (int i = 0; i < 4; i++) { v[i] = hp[t * 4 + i]; hp[t * 4 + i] = 0ull; }
  if (t == 0) s_bs = 1023;
  sc[t] = v[0] + v[1] + v[2] + v[3];
  __syncthreads();
  for (int off = 1; off < 256; off <<= 1) {
    unsigned long long add = (t + off < 256) ? sc[t + off] : 0ull;
    __syncthreads();
    sc[t] += add;
    __syncthreads();
  }
  const unsigned long long totalP = sc[0];
  unsigned long long run = (t < 255) ? sc[t + 1] : 0ull;
  suf[t * 4 + 3] = run; run += v[3];
  suf[t * 4 + 2] = run; run += v[2];
  suf[t * 4 + 1] = run; run += v[1];
  suf[t * 4 + 0] = run;
  __syncthreads();

  RowP2 p;
  unsigned long long base, toppZ;
  int ktop_;
  if (level == 0) {
    ktop_ = topk_a[b];
    unsigned long long Zfix = totalP & SMASK;
    if (!Zfix) Zfix = 1ull;
    toppZ = (unsigned long long)((double)topp_a[b] * (double)Zfix);
    base = 0ull;
    p.pfx = 0; p.invZ = (float)(FIX2 / (double)Zfix);
    p.ustar = 0; p.m = 0; p.cEq = 0;
  } else {
    p = params[b];
    base = p.basePack; toppZ = p.toppZfix; ktop_ = p.ktop;
  }

#pragma unroll
  for (int i = 0; i < 4; i++) {
    const int bin = t * 4 + i;
    const unsigned long long sG = base + suf[bin];
    const bool A = ((long long)(sG >> 48) < (long long)ktop_) && ((sG & SMASK) <= toppZ);
    const unsigned long long sPfull = base + ((bin > 0) ? suf[bin - 1] : totalP);
    const bool Ap = ((long long)(sPfull >> 48) < (long long)ktop_) && ((sPfull & SMASK) <= toppZ);
    if (A && !Ap) s_bs = bin;
  }
  __syncthreads();
  if (t == 0) {
    const int bs = s_bs;
    const unsigned long long newBase = base + suf[bs];
    if (level < 2) {
      p.basePack = newBase;
      p.toppZfix = toppZ;
      p.ktop = ktop_;
      p.pfx = (level == 0) ? (unsigned)bs : ((p.pfx << 10) | (unsigned)bs);
      params[b] = p;
    } else {
      const unsigned ustar = (p.pfx << 10) | (unsigned)bs;
      const unsigned long long raw = ((bs > 0) ? suf[bs - 1] : totalP) - suf[bs];
      const int cEq = (int)(raw >> 48);
      const long long Chi = (long long)(newBase >> 48);
      const unsigned long long Shi = newBase & SMASK;
      long long m = cEq;
      const long long lim = (long long)ktop_ - Chi;
      if (lim < m) m = lim;
      const double tf = (double)__uint_as_float(ustar) * FIX2;
      const double rem = (double)(toppZ - Shi);
      const double Rd = floor(rem / tf) + 1.0;
      if (Rd < (double)m) m = (long long)Rd;
      if (m < 1) m = 1;
      p.ustar = ustar; p.m = (int)m; p.cEq = cEq;
      params[b] = p;
    }
  }
}

// ---------------- S3: final filter (sentinel −e only if ties must be ranked) --------
__global__ __launch_bounds__(256) void s3_filter(
    float* __restrict__ buf, const RowP2* __restrict__ params) {
  const int b = blockIdx.x >> 3, sl = blockIdx.x & 7, t = threadIdx.x;
  const RowP2 p = params[b];
  const unsigned ustar = p.ustar;
  const float invZ = p.invZ;
  const bool need = (p.m < p.cEq);
  float* row = buf + (size_t)b * NV;
  const int base = sl * 4096;
#pragma unroll
  for (int it = 0; it < 4; it++) {
    const int idx = base + (it * 256 + t) * 4;
    if (idx < NV) {
      float4 e4 = *(const float4*)(row + idx);
      float4 o4;
      unsigned k;
      k = __float_as_uint(e4.x);
      o4.x = (k > ustar) ? e4.x * invZ : ((k == ustar) ? (need ? -e4.x : e4.x * invZ) : 0.f);
      k = __float_as_uint(e4.y);
      o4.y = (k > ustar) ? e4.y * invZ : ((k == ustar) ? (need ? -e4.y : e4.y * invZ) : 0.f);
      k = __float_as_uint(e4.z);
      o4.z = (k > ustar) ? e4.z * invZ : ((k == ustar) ? (need ? -e4.z : e4.z * invZ) : 0.f);
      k = __float_as_uint(e4.w);
      o4.w = (k > ustar) ? e4.w * invZ : ((k == ustar) ? (need ? -e4.w : e4.w * invZ) : 0.f);
      *(float4*)(row + idx) = o4;
    }
  }
}

// ---------------- S5: rare tie-rank fixup (no-op unless m < cEq) ----------------
__global__ __launch_bounds__(256) void s5_tie(
    float* __restrict__ buf, const RowP2* __restrict__ params) {
  const int b = blockIdx.x, t = threadIdx.x;
  const RowP2 p = params[b];
  if (p.m >= p.cEq) return;
  const int m = p.m;
  const float invZ = p.invZ;
  float* row = buf + (size_t)b * NV;
  __shared__ int s_rank[256];
  const int CH = NV / 256;  // 125
  const int base = t * CH, end = base + CH;
  int myc = 0;
  for (int v = base; v < end; v++) myc += (row[v] < 0.f);
  s_rank[t] = myc;
  __syncthreads();
  for (int off = 1; off < 256; off <<= 1) {
    const int v0 = s_rank[t];
    const int vn = (t >= off) ? s_rank[t - off] : 0;
    __syncthreads();
    s_rank[t] = v0 + vn;
    __syncthreads();
  }
  int r = (t > 0) ? s_rank[t - 1] : 0;
  for (int v = base; v < end; v++) {
    const float f = row[v];
    if (f < 0.f) {
      row[v] = (r < m) ? (-f) * invZ : 0.f;
      r++;
    }
  }
}

extern "C" void kernel_launch(void* const* d_in, const int* in_sizes, int n_in,
                              void* d_out, int out_size, void* d_ws, size_t ws_size,
                              hipStream_t stream) {
  (void)in_sizes; (void)n_in; (void)out_size; (void)ws_size;
  const float* hidden = (const float*)d_in[0];
  const float* emb    = (const float*)d_in[1];
  const int*   toks   = (const int*)d_in[2];
  const float* pres   = (const float*)d_in[3];
  const float* freq   = (const float*)d_in[4];
  const float* temp   = (const float*)d_in[5];
  const float* topp   = (const float*)d_in[6];
  const int*   topk   = (const int*)d_in[7];
  float* out = (float*)d_out;

  // ws layout (total ≈ 3.95 MB)
  const size_t offA3   = 0;                       // 1,835,008 B
  const size_t offRM   = 1835008;                 // 1,024 B  (zeroed)
  const size_t offHist = offRM + 1024;            // 2,097,152 B (zeroed)
  const size_t offMr   = offHist + 2097152;       // 1,024 B
  const size_t offPar  = offMr + 1024;            // 256*40 B

  _Float16* A3 = (_Float16*)((char*)d_ws + offA3);
  unsigned* rowmax = (unsigned*)((char*)d_ws + offRM);
  unsigned long long* histP = (unsigned long long*)((char*)d_ws + offHist);
  float* Mrow = (float*)((char*)d_ws + offMr);
  RowP2* params = (RowP2*)((char*)d_ws + offPar);

  hipMemsetAsync((char*)d_ws + offRM, 0, 1024 + 2097152, stream);
  convert_A<<<NKB, 256, 0, stream>>>(hidden, A3);
  gemm_f16s<<<NGBLK, 256, 0, stream>>>(emb, A3, temp, rowmax, out);
  s0_prep<<<NB, 64, 0, stream>>>(rowmax, toks, pres, freq, temp, Mrow, out);
  h_l0<<<NB * 8, 256, 0, stream>>>(out, Mrow, histP);
  s2_level<<<NB, 256, 0, stream>>>(histP, topp, topk, params, 0);
  h_ref<<<NB * 8, 256, 0, stream>>>(out, params, histP, 20, 10);
  s2_level<<<NB, 256, 0, stream>>>(histP, topp, topk, params, 1);
  h_ref<<<NB * 8, 256, 0, stream>>>(out, params, histP, 10, 0);
  s2_level<<<NB, 256, 0, stream>>>(histP, topp, topk, params, 2);
  s3_filter<<<NB * 8, 256, 0, stream>>>(out, params);
  s5_tie<<<NB, 256, 0, stream>>>(out, params);
}